// Round 2
// baseline (155.988 us; speedup 1.0000x reference)
//
#include <hip/hip_runtime.h>
#include <cstddef>

#define EPS 1e-5f
static constexpr int Bn = 64, Cn = 64, Hn = 56, Wn = 56, HWn = Hn * Wn; // 3136
static constexpr int XS = 65; // k1 LDS transpose stride (floats): 2-way max on write & read
static constexpr int RB = 4;          // rows per band in fused k23
static constexpr int NBAND = 14;      // 56 / 4
static constexpr int BPX = RB * Wn;   // 224 px per band
static constexpr int SLAB = 1808;     // ushorts per cat slab: 224*8 + 16 pad (3616 B == 8 dwords mod 32 banks -> quad offsets {0,8,16,24})

typedef __attribute__((ext_vector_type(8))) short short8;
typedef __attribute__((ext_vector_type(8))) unsigned short ushort8;
typedef __attribute__((ext_vector_type(4))) float floatx4;
typedef __attribute__((ext_vector_type(16))) float floatx16;
typedef __attribute__((ext_vector_type(4))) unsigned int uintx4;
typedef __attribute__((ext_vector_type(2))) unsigned int uintx2;

__device__ __forceinline__ unsigned pack_rne(float a, float b) {
    unsigned ua = __float_as_uint(a), ub = __float_as_uint(b);
    ua = ua + 0x7fffu + ((ua >> 16) & 1u);
    ub = ub + 0x7fffu + ((ub >> 16) & 1u);
    return __builtin_amdgcn_perm(ub, ua, 0x07060302);
}
__device__ __forceinline__ unsigned pack_trunc(float a, float b) {
    return __builtin_amdgcn_perm(__float_as_uint(b), __float_as_uint(a), 0x07060302);
}
__device__ __forceinline__ ushort8 pmax(ushort8 a, ushort8 b) {
    return __builtin_elementwise_max(a, b);   // valid bf16 max for values >= 0
}
__device__ __forceinline__ float bf_lo(unsigned u) { return __uint_as_float(u << 16); }
__device__ __forceinline__ float bf_hi(unsigned u) { return __uint_as_float(u & 0xffff0000u); }

// Layouts (bf16):
//   node0: [b][chunk=8][px=3136][j=8]
//   cat (LDS, per 4-row band): 16 slabs of SLAB ushorts; slab = chunk*2 + plane
//     (plane 0 = avg, 1 = maxsum), element [px_local=224][j=8]

// ---------------------------------------------------------------------------
// K1: node0 = relu(bn1(conv1x1(x,w1))). Unchanged.
// ---------------------------------------------------------------------------
__global__ __launch_bounds__(256) void k1_conv1(
    const float* __restrict__ x, const float* __restrict__ w1,
    const float* __restrict__ bg, const float* __restrict__ bb,
    const float* __restrict__ bm, const float* __restrict__ bv,
    unsigned short* __restrict__ node0)
{
    __shared__ float xs[2][64 * XS];   // 2 x 16.6 KB px-major fp32 tiles
    __shared__ float scs[64], shs[64];
    const int tid = threadIdx.x;
    if (tid < 64) {
        float sc = bg[tid] * rsqrtf(bv[tid] + EPS);
        scs[tid] = sc;
        shs[tid] = bb[tid] - bm[tid] * sc;
    }
    __syncthreads();
    const int lane = tid & 63;
    const int wv   = tid >> 6;
    const int m    = lane & 15;
    const int quad = lane >> 4;
    const int qoff = quad * 8;

    short8 afr[4][2];
    float shv[16];
    #pragma unroll
    for (int t = 0; t < 4; ++t) {
        const float sc = scs[t * 16 + m];
        #pragma unroll
        for (int kk = 0; kk < 2; ++kk) {
            const float* wp = w1 + (t * 16 + m) * 64 + kk * 32 + qoff;
            floatx4 f0 = *(const floatx4*)wp;
            floatx4 f1 = *(const floatx4*)(wp + 4);
            uintx4 u;
            u.x = pack_rne(f0[0] * sc, f0[1] * sc);
            u.y = pack_rne(f0[2] * sc, f0[3] * sc);
            u.z = pack_rne(f1[0] * sc, f1[1] * sc);
            u.w = pack_rne(f1[2] * sc, f1[3] * sc);
            afr[t][kk] = *(short8*)&u;
        }
        #pragma unroll
        for (int i = 0; i < 4; ++i) shv[t * 4 + i] = shs[t * 16 + quad * 4 + i];
    }

    floatx4 stg[4];
    auto ldtile = [&](int tt) {
        const int P = blockIdx.x * 256 + tt * 64;
        const int b = P / HWn, p0 = P - b * HWn;   // 64 | 3136: no image crossing
        #pragma unroll
        for (int q = 0; q < 4; ++q) {
            int idx = q * 256 + tid;               // (c = idx/16, f = idx%16)
            int c = idx >> 4, f = idx & 15;
            stg[q] = *(const floatx4*)(x + (size_t)(b * 64 + c) * HWn + p0 + f * 4);
        }
    };
    auto sttile = [&](int buf) {
        #pragma unroll
        for (int q = 0; q < 4; ++q) {
            int idx = q * 256 + tid;
            int c = idx >> 4, f = idx & 15;
            #pragma unroll
            for (int k = 0; k < 4; ++k)
                xs[buf][(f * 4 + k) * XS + c] = stg[q][k];   // 2-way banks (XS=65)
        }
    };

    ldtile(0);
    sttile(0);

    #pragma unroll
    for (int tt = 0; tt < 4; ++tt) {
        __syncthreads();                 // xs[tt&1] ready for all threads
        if (tt < 3) ldtile(tt + 1);      // global loads overlap compute

        const int P = blockIdx.x * 256 + tt * 64;
        const int b = P / HWn, p0 = P - b * HWn;
        const float* xr = &xs[tt & 1][(wv * 16 + m) * XS];

        floatx4 acc[4];
        #pragma unroll
        for (int t = 0; t < 4; ++t) acc[t] = (floatx4){0.f, 0.f, 0.f, 0.f};

        #pragma unroll
        for (int kk = 0; kk < 2; ++kk) {
            float f[8];
            #pragma unroll
            for (int j = 0; j < 8; ++j) f[j] = xr[kk * 32 + qoff + j];  // 2-way banks
            uintx4 u;
            u.x = pack_trunc(f[0], f[1]);
            u.y = pack_trunc(f[2], f[3]);
            u.z = pack_trunc(f[4], f[5]);
            u.w = pack_trunc(f[6], f[7]);
            short8 bfr = *(short8*)&u;
            #pragma unroll
            for (int t = 0; t < 4; ++t)
                acc[t] = __builtin_amdgcn_mfma_f32_16x16x32_bf16(afr[t][kk], bfr, acc[t], 0, 0, 0);
        }

        const int chunkbase = (quad >> 1);
        const int j0 = (quad & 1) * 4;
        #pragma unroll
        for (int t = 0; t < 4; ++t) {
            float v0 = acc[t][0] + shv[t * 4 + 0]; v0 = v0 > 0.f ? v0 : 0.f;
            float v1 = acc[t][1] + shv[t * 4 + 1]; v1 = v1 > 0.f ? v1 : 0.f;
            float v2 = acc[t][2] + shv[t * 4 + 2]; v2 = v2 > 0.f ? v2 : 0.f;
            float v3 = acc[t][3] + shv[t * 4 + 3]; v3 = v3 > 0.f ? v3 : 0.f;
            uintx2 st;
            st.x = pack_rne(v0, v1);
            st.y = pack_rne(v2, v3);
            int chunk = t * 2 + chunkbase;
            *(uintx2*)(node0 + ((size_t)(b * 8 + chunk) * HWn + p0 + wv * 16 + m) * 8 + j0) = st;
        }

        if (tt < 3) sttile((tt + 1) & 1);   // write next buffer; sync at loop top
    }
}

// ---------------------------------------------------------------------------
// K23: fused pools + conv2. Block = (b, 4-row band), 512 thr = 8 waves.
// RB=4 -> 56.5 KB LDS -> 2 blocks/CU (4 waves/SIMD): pool phase of one block
// overlaps MFMA phase of the co-resident block.
// Pool loads only the center column per row (1 ushort8); +-1/+-2 column taps
// derived via __shfl (identical values to the old 5-tap loads).
// ---------------------------------------------------------------------------
__global__ __launch_bounds__(512, 4) void k23_fused(
    const unsigned short* __restrict__ node0,
    const float* __restrict__ w2,
    const float* __restrict__ bg, const float* __restrict__ bb,
    const float* __restrict__ bm, const float* __restrict__ bv,
    float* __restrict__ out)
{
    __shared__ __align__(16) unsigned short catl[16 * SLAB];  // 56.5 KB
    const int tid = threadIdx.x;
    const int lane = tid & 63;
    const int wv = tid >> 6;            // 0..7

    // XCD-aware bijective swizzle (896 = 8*112): each XCD keeps 8 full images
    // (3.2 MB node0 slice < 4 MB L2) so band-halo re-reads are L2 hits.
    int bid = blockIdx.x;
    bid = (bid & 7) * 112 + (bid >> 3);
    const int band = bid % NBAND;
    const int b = bid / NBAND;
    const int lo = band * RB;

    const int m = lane & 15;
    const int q = lane >> 4;
    const int t = wv >> 1;              // out-ch tile 0..3 (waves 2t, 2t+1 share t)

    // ---- Phase 1: pool chunk wv into catl ----
    {
        const int chunk = wv;
        const int col = lane;
        const bool act = col < Wn;
        const unsigned short* base = node0 + ((size_t)(b * 8 + chunk) * HWn) * 8;
        unsigned short* cav = catl + (size_t)(chunk * 2 + 0) * SLAB;
        unsigned short* cmx = catl + (size_t)(chunk * 2 + 1) * SLAB;

        const ushort8 zz = (ushort8)0;
        auto loadrow = [&](int r) -> ushort8 {
            bool ok = act && ((unsigned)r < (unsigned)Hn);
            return ok ? *(const ushort8*)(base + (size_t)(r * Wn + col) * 8) : zz;
        };

        float hs1[8], hs2[8];
        ushort8 h5a = zz, h5b = zz, h5c = zz, h5d = zz, nh1 = zz, nh2 = zz;
        #pragma unroll
        for (int j = 0; j < 8; ++j) hs1[j] = hs2[j] = 0.f;

        ushort8 cur = loadrow(lo - 2);

        #pragma unroll
        for (int i = 0; i < RB + 4; ++i) {
            const int r = lo - 2 + i;
            ushort8 nxt = zz;
            if (i < RB + 3) nxt = loadrow(r + 1);    // prefetch next row

            // column taps via shuffles (lanes >=56 hold zz -> right edge is 0)
            const uintx4 uc = *(const uintx4*)&cur;
            uintx4 t0, t1, t3, t4;
            #pragma unroll
            for (int w = 0; w < 4; ++w) {
                unsigned u = uc[w];
                unsigned l1 = __shfl_up(u, 1);
                unsigned l2 = __shfl_up(u, 2);
                unsigned r1 = __shfl_down(u, 1);
                unsigned r2v = __shfl_down(u, 2);
                t0[w] = (lane < 2) ? 0u : l2;
                t1[w] = (lane < 1) ? 0u : l1;
                t3[w] = r1;
                t4[w] = r2v;
            }
            const ushort8 D0 = *(const ushort8*)&t0;
            const ushort8 D1 = *(const ushort8*)&t1;
            const ushort8 D3 = *(const ushort8*)&t3;
            const ushort8 D4 = *(const ushort8*)&t4;

            ushort8 hm5 = pmax(pmax(pmax(D0, D1), pmax(cur, D3)), D4);
            ushort8 m5 = pmax(pmax(pmax(h5a, h5b), pmax(h5c, h5d)), hm5);
            h5a = h5b; h5b = h5c; h5c = h5d; h5d = hm5;

            const uintx4 ul = t1;
            const uintx4 uv = uc;
            const uintx4 ur = t3;
            float a2[8];
            const int r2 = r - 1, r3 = r - 2;
            const bool v2 = ((unsigned)r2 < (unsigned)Hn) && act;  // act: lane56 ap must stay 0
            #pragma unroll
            for (int w = 0; w < 4; ++w) {
                float hsum0 = bf_lo(ul[w]) + bf_lo(uv[w]) + bf_lo(ur[w]);
                float hsum1 = bf_hi(ul[w]) + bf_hi(uv[w]) + bf_hi(ur[w]);
                a2[w * 2 + 0] = v2 ? (hs2[w * 2 + 0] + hs1[w * 2 + 0] + hsum0) * (1.f / 9.f) : 0.f;
                a2[w * 2 + 1] = v2 ? (hs2[w * 2 + 1] + hs1[w * 2 + 1] + hsum1) * (1.f / 9.f) : 0.f;
                hs2[w * 2 + 0] = hs1[w * 2 + 0]; hs1[w * 2 + 0] = hsum0;
                hs2[w * 2 + 1] = hs1[w * 2 + 1]; hs1[w * 2 + 1] = hsum1;
            }
            uintx4 ap;
            ap.x = pack_rne(a2[0], a2[1]);
            ap.y = pack_rne(a2[2], a2[3]);
            ap.z = pack_rne(a2[4], a2[5]);
            ap.w = pack_rne(a2[6], a2[7]);
            uintx4 al, ar;
            #pragma unroll
            for (int w = 0; w < 4; ++w) {
                unsigned u = ap[w];
                unsigned lu = __shfl_up(u, 1);
                unsigned ru = __shfl_down(u, 1);
                al[w] = (lane == 0) ? 0u : lu;
                ar[w] = (lane == 63) ? 0u : ru;
            }
            ushort8 nh = pmax(pmax(*(ushort8*)&al, *(ushort8*)&ap), *(ushort8*)&ar);
            ushort8 m3 = pmax(pmax(nh2, nh1), nh);
            nh2 = nh1; nh1 = nh;

            if (act && r2 >= lo && r2 < lo + RB)
                *(uintx4*)(cav + (size_t)((r2 - lo) * Wn + col) * 8) = ap;
            if (act && r3 >= lo && r3 < lo + RB) {
                const uintx4 u5 = *(const uintx4*)&m5;
                const uintx4 u3 = *(const uintx4*)&m3;
                uintx4 st;
                #pragma unroll
                for (int w = 0; w < 4; ++w)
                    st[w] = pack_rne(bf_lo(u5[w]) + bf_lo(u3[w]), bf_hi(u5[w]) + bf_hi(u3[w]));
                *(uintx4*)(cmx + (size_t)((r3 - lo) * Wn + col) * 8) = st;
            }
            cur = nxt;
        }
    }

    // ---- A-frags (w2 in k-slot layout) + bn2 constants: loads issue here,
    //      latency hides under the barrier wait ----
    short8 afr[4];
    #pragma unroll
    for (int cp = 0; cp < 4; ++cp) {
        const int c = 2 * cp + (q >> 1);
        const int chb = ((q & 1) ? 64 : 0) + 8 * c;   // k-slot -> cat channel base
        const float* wp = w2 + (size_t)(t * 16 + m) * 128 + chb;
        floatx4 f0 = *(const floatx4*)wp;
        floatx4 f1 = *(const floatx4*)(wp + 4);
        uintx4 u;
        u.x = pack_rne(f0[0], f0[1]);
        u.y = pack_rne(f0[2], f0[3]);
        u.z = pack_rne(f1[0], f1[1]);
        u.w = pack_rne(f1[2], f1[3]);
        afr[cp] = *(short8*)&u;
    }
    const int oc0 = t * 16 + q * 4;     // this lane's 4 output channels (C rows)
    floatx4 g4 = *(const floatx4*)(bg + oc0);
    floatx4 bb4 = *(const floatx4*)(bb + oc0);
    floatx4 mm4 = *(const floatx4*)(bm + oc0);
    floatx4 vv4 = *(const floatx4*)(bv + oc0);
    float sc[4], sh[4];
    #pragma unroll
    for (int r = 0; r < 4; ++r) {
        sc[r] = g4[r] * rsqrtf(vv4[r] + EPS);
        sh[r] = bb4[r] - mm4[r] * sc[r];
    }
    __syncthreads();

    // ---- Phase 2: MFMA. Wave covers t = wv>>1, px tiles (wv&1)*7 .. +6 ----
    floatx4 acc[7];
    #pragma unroll
    for (int i = 0; i < 7; ++i) acc[i] = (floatx4){0.f, 0.f, 0.f, 0.f};

    #pragma unroll
    for (int cp = 0; cp < 4; ++cp) {
        #pragma unroll
        for (int i = 0; i < 7; ++i) {
            const int px = ((wv & 1) * 7 + i) * 16 + m;
            // slab = 4*cp + q: quads land at bank offsets {0,8,16,24} -> 2 lanes/bank
            short8 bfr = *(const short8*)(catl + (size_t)(4 * cp + q) * SLAB + (size_t)px * 8);
            acc[i] = __builtin_amdgcn_mfma_f32_16x16x32_bf16(afr[cp], bfr, acc[i], 0, 0, 0);
        }
    }

    // ---- epilogue: bn2 + relu + fp32 store ----
    float* ob = out + (size_t)(b * 64 + oc0) * HWn + lo * Wn;
    #pragma unroll
    for (int i = 0; i < 7; ++i) {
        const int px = ((wv & 1) * 7 + i) * 16 + m;
        #pragma unroll
        for (int r = 0; r < 4; ++r) {
            float v = fmaf(acc[i][r], sc[r], sh[r]);
            ob[(size_t)r * HWn + px] = v > 0.f ? v : 0.f;
        }
    }
}

extern "C" void kernel_launch(void* const* d_in, const int* in_sizes, int n_in,
                              void* d_out, int out_size, void* d_ws, size_t ws_size,
                              hipStream_t stream)
{
    const float* x   = (const float*)d_in[0];
    const float* w1  = (const float*)d_in[1];
    const float* w2  = (const float*)d_in[2];
    const float* b1g = (const float*)d_in[3];
    const float* b1b = (const float*)d_in[4];
    const float* b1m = (const float*)d_in[5];
    const float* b1v = (const float*)d_in[6];
    const float* b2g = (const float*)d_in[7];
    const float* b2b = (const float*)d_in[8];
    const float* b2m = (const float*)d_in[9];
    const float* b2v = (const float*)d_in[10];

    float* out = (float*)d_out;
    unsigned short* node0 = (unsigned short*)d_ws;            // 25.7 MB

    k1_conv1<<<dim3(784), dim3(256), 0, stream>>>(x, w1, b1g, b1b, b1m, b1v, node0);
    k23_fused<<<dim3(Bn * NBAND), dim3(512), 0, stream>>>(node0, w2, b2g, b2b, b2m, b2v, out);
}

// Round 3
// 146.624 us; speedup vs baseline: 1.0639x; 1.0639x over previous
//
#include <hip/hip_runtime.h>
#include <cstddef>

#define EPS 1e-5f
static constexpr int Bn = 64, Cn = 64, Hn = 56, Wn = 56, HWn = Hn * Wn; // 3136
static constexpr int XS = 65; // k1 LDS transpose stride (floats): 2-way max on write & read
static constexpr int RB = 8;          // rows per band in fused k23
static constexpr int NBAND = 7;       // 56 / 8
static constexpr int SLAB = 3600;     // ushorts per cat slab: 448*8 + 16 pad (7200 B -> quad bank offsets {0,8,16,24})

typedef __attribute__((ext_vector_type(8))) short short8;
typedef __attribute__((ext_vector_type(8))) unsigned short ushort8;
typedef __attribute__((ext_vector_type(4))) unsigned short ushort4v;
typedef __attribute__((ext_vector_type(4))) float floatx4;
typedef __attribute__((ext_vector_type(4))) unsigned int uintx4;
typedef __attribute__((ext_vector_type(2))) unsigned int uintx2;

__device__ __forceinline__ unsigned pack_rne(float a, float b) {
    unsigned ua = __float_as_uint(a), ub = __float_as_uint(b);
    ua = ua + 0x7fffu + ((ua >> 16) & 1u);
    ub = ub + 0x7fffu + ((ub >> 16) & 1u);
    return __builtin_amdgcn_perm(ub, ua, 0x07060302);
}
__device__ __forceinline__ unsigned pack_trunc(float a, float b) {
    return __builtin_amdgcn_perm(__float_as_uint(b), __float_as_uint(a), 0x07060302);
}
__device__ __forceinline__ ushort8 pmax(ushort8 a, ushort8 b) {
    return __builtin_elementwise_max(a, b);   // valid bf16 max for values >= 0
}
__device__ __forceinline__ uintx2 pmax2(uintx2 a, uintx2 b) {
    ushort4v r = __builtin_elementwise_max(*(ushort4v*)&a, *(ushort4v*)&b);
    return *(uintx2*)&r;
}
__device__ __forceinline__ float bf_lo(unsigned u) { return __uint_as_float(u << 16); }
__device__ __forceinline__ float bf_hi(unsigned u) { return __uint_as_float(u & 0xffff0000u); }

// Layouts (bf16):
//   node0: [b][chunk=8][px=3136][j=8]
//   cat (LDS, per 8-row band): 16 slabs of SLAB ushorts; slab = chunk*2 + plane
//     (plane 0 = avg, 1 = maxsum), element [px_local=448][j=8]

// ---------------------------------------------------------------------------
// K1: node0 = relu(bn1(conv1x1(x,w1))). Unchanged.
// ---------------------------------------------------------------------------
__global__ __launch_bounds__(256) void k1_conv1(
    const float* __restrict__ x, const float* __restrict__ w1,
    const float* __restrict__ bg, const float* __restrict__ bb,
    const float* __restrict__ bm, const float* __restrict__ bv,
    unsigned short* __restrict__ node0)
{
    __shared__ float xs[2][64 * XS];   // 2 x 16.6 KB px-major fp32 tiles
    __shared__ float scs[64], shs[64];
    const int tid = threadIdx.x;
    if (tid < 64) {
        float sc = bg[tid] * rsqrtf(bv[tid] + EPS);
        scs[tid] = sc;
        shs[tid] = bb[tid] - bm[tid] * sc;
    }
    __syncthreads();
    const int lane = tid & 63;
    const int wv   = tid >> 6;
    const int m    = lane & 15;
    const int quad = lane >> 4;
    const int qoff = quad * 8;

    short8 afr[4][2];
    float shv[16];
    #pragma unroll
    for (int t = 0; t < 4; ++t) {
        const float sc = scs[t * 16 + m];
        #pragma unroll
        for (int kk = 0; kk < 2; ++kk) {
            const float* wp = w1 + (t * 16 + m) * 64 + kk * 32 + qoff;
            floatx4 f0 = *(const floatx4*)wp;
            floatx4 f1 = *(const floatx4*)(wp + 4);
            uintx4 u;
            u.x = pack_rne(f0[0] * sc, f0[1] * sc);
            u.y = pack_rne(f0[2] * sc, f0[3] * sc);
            u.z = pack_rne(f1[0] * sc, f1[1] * sc);
            u.w = pack_rne(f1[2] * sc, f1[3] * sc);
            afr[t][kk] = *(short8*)&u;
        }
        #pragma unroll
        for (int i = 0; i < 4; ++i) shv[t * 4 + i] = shs[t * 16 + quad * 4 + i];
    }

    floatx4 stg[4];
    auto ldtile = [&](int tt) {
        const int P = blockIdx.x * 256 + tt * 64;
        const int b = P / HWn, p0 = P - b * HWn;   // 64 | 3136: no image crossing
        #pragma unroll
        for (int q = 0; q < 4; ++q) {
            int idx = q * 256 + tid;               // (c = idx/16, f = idx%16)
            int c = idx >> 4, f = idx & 15;
            stg[q] = *(const floatx4*)(x + (size_t)(b * 64 + c) * HWn + p0 + f * 4);
        }
    };
    auto sttile = [&](int buf) {
        #pragma unroll
        for (int q = 0; q < 4; ++q) {
            int idx = q * 256 + tid;
            int c = idx >> 4, f = idx & 15;
            #pragma unroll
            for (int k = 0; k < 4; ++k)
                xs[buf][(f * 4 + k) * XS + c] = stg[q][k];   // 2-way banks (XS=65)
        }
    };

    ldtile(0);
    sttile(0);

    #pragma unroll
    for (int tt = 0; tt < 4; ++tt) {
        __syncthreads();                 // xs[tt&1] ready for all threads
        if (tt < 3) ldtile(tt + 1);      // global loads overlap compute

        const int P = blockIdx.x * 256 + tt * 64;
        const int b = P / HWn, p0 = P - b * HWn;
        const float* xr = &xs[tt & 1][(wv * 16 + m) * XS];

        floatx4 acc[4];
        #pragma unroll
        for (int t = 0; t < 4; ++t) acc[t] = (floatx4){0.f, 0.f, 0.f, 0.f};

        #pragma unroll
        for (int kk = 0; kk < 2; ++kk) {
            float f[8];
            #pragma unroll
            for (int j = 0; j < 8; ++j) f[j] = xr[kk * 32 + qoff + j];  // 2-way banks
            uintx4 u;
            u.x = pack_trunc(f[0], f[1]);
            u.y = pack_trunc(f[2], f[3]);
            u.z = pack_trunc(f[4], f[5]);
            u.w = pack_trunc(f[6], f[7]);
            short8 bfr = *(short8*)&u;
            #pragma unroll
            for (int t = 0; t < 4; ++t)
                acc[t] = __builtin_amdgcn_mfma_f32_16x16x32_bf16(afr[t][kk], bfr, acc[t], 0, 0, 0);
        }

        const int chunkbase = (quad >> 1);
        const int j0 = (quad & 1) * 4;
        #pragma unroll
        for (int t = 0; t < 4; ++t) {
            float v0 = acc[t][0] + shv[t * 4 + 0]; v0 = v0 > 0.f ? v0 : 0.f;
            float v1 = acc[t][1] + shv[t * 4 + 1]; v1 = v1 > 0.f ? v1 : 0.f;
            float v2 = acc[t][2] + shv[t * 4 + 2]; v2 = v2 > 0.f ? v2 : 0.f;
            float v3 = acc[t][3] + shv[t * 4 + 3]; v3 = v3 > 0.f ? v3 : 0.f;
            uintx2 st;
            st.x = pack_rne(v0, v1);
            st.y = pack_rne(v2, v3);
            int chunk = t * 2 + chunkbase;
            *(uintx2*)(node0 + ((size_t)(b * 8 + chunk) * HWn + p0 + wv * 16 + m) * 8 + j0) = st;
        }

        if (tt < 3) sttile((tt + 1) & 1);   // write next buffer; sync at loop top
    }
}

// ---------------------------------------------------------------------------
// K23: fused pools + conv2. Block = (b, 8-row band), 1024 thr = 16 waves.
// RB=8: 12 pool iters per 8 output rows (1.5x halo, half the VALU of RB=4).
// Pool wave = (chunk = wv>>1, col-half = wv&1); lane = (col, 4-ch half):
// all 64 lanes active, 4 waves/SIMD, ushort4 granularity, shuffle taps with
// even lane deltas (jh parity preserved), no edge masks (zero-pad dominated:
// all values >= 0 after relu, so clipped windows are automatically <= the
// in-image neighbor and never win the max; avg pads are genuine zeros).
// Phase 2: 16x16x32 MFMA vs w2, t = wv&3, px-quarter = wv>>2.
// ---------------------------------------------------------------------------
__global__ __launch_bounds__(1024, 4) void k23_fused(
    const unsigned short* __restrict__ node0,
    const float* __restrict__ w2,
    const float* __restrict__ bg, const float* __restrict__ bb,
    const float* __restrict__ bm, const float* __restrict__ bv,
    float* __restrict__ out)
{
    __shared__ __align__(16) unsigned short catl[16 * SLAB];  // 115.2 KB
    const int tid = threadIdx.x;
    const int lane = tid & 63;
    const int wv = tid >> 6;            // 0..15

    // XCD-aware bijective swizzle (448 = 8*56): each XCD keeps 8 images
    // together so band-halo re-reads of node0 are L2 hits.
    const int bid = blockIdx.x;
    const int xcd = bid & 7;
    const int jj = bid >> 3;            // 0..55
    const int b = xcd * 8 + jj / NBAND;
    const int band = jj % NBAND;
    const int lo = band * RB;

    // ---- Phase 1: pool (chunk, col-half) into catl ----
    {
        const int chunk = wv >> 1;
        const int c0 = (wv & 1) * 28;
        const int local = lane >> 1;        // 0..31; computed cols = locals 2..29
        const int col = c0 - 2 + local;
        const int jh = lane & 1;            // 4-channel half
        const unsigned short* base = node0 + ((size_t)(b * 8 + chunk) * HWn) * 8 + jh * 4;

        const uintx2 zz = (uintx2){0u, 0u};
        auto loadrow = [&](int r) -> uintx2 {
            if (((unsigned)col >= (unsigned)Wn) | ((unsigned)r >= (unsigned)Hn)) return zz;
            return *(const uintx2*)(base + (size_t)(r * Wn + col) * 8);
        };

        float hs1[4], hs2[4];
        #pragma unroll
        for (int c = 0; c < 4; ++c) hs1[c] = hs2[c] = 0.f;
        uintx2 h5a = zz, h5b = zz, h5c = zz, h5d = zz, nh1 = zz, nh2 = zz;

        uintx2 cur = loadrow(lo - 2);
        uintx2 nxt = loadrow(lo - 1);

        unsigned short* cav = catl + (size_t)(chunk * 2) * SLAB + jh * 4;
        unsigned short* cmx = cav + SLAB;
        const bool stcol = (local >= 2) & (local <= 29);

        #pragma unroll
        for (int i = 0; i < RB + 4; ++i) {
            const int r = lo - 2 + i;
            uintx2 nx2 = (i < RB + 2) ? loadrow(r + 2) : zz;   // 2-deep prefetch

            // column taps via even-delta shuffles (jh parity preserved)
            uintx2 D0, D1, D3, D4;
            #pragma unroll
            for (int w = 0; w < 2; ++w) {
                unsigned u = cur[w];
                D1[w] = __shfl_up(u, 2);
                D0[w] = __shfl_up(u, 4);
                D3[w] = __shfl_down(u, 2);
                D4[w] = __shfl_down(u, 4);
            }

            uintx2 hm5 = pmax2(pmax2(pmax2(D0, D1), pmax2(cur, D3)), D4);
            uintx2 m5 = pmax2(pmax2(pmax2(h5a, h5b), pmax2(h5c, h5d)), hm5);
            h5a = h5b; h5b = h5c; h5c = h5d; h5d = hm5;

            float a2[4];
            #pragma unroll
            for (int w = 0; w < 2; ++w) {
                float s0 = bf_lo(D1[w]) + bf_lo(cur[w]) + bf_lo(D3[w]);
                float s1 = bf_hi(D1[w]) + bf_hi(cur[w]) + bf_hi(D3[w]);
                a2[w * 2 + 0] = (hs2[w * 2 + 0] + hs1[w * 2 + 0] + s0) * (1.f / 9.f);
                a2[w * 2 + 1] = (hs2[w * 2 + 1] + hs1[w * 2 + 1] + s1) * (1.f / 9.f);
                hs2[w * 2 + 0] = hs1[w * 2 + 0]; hs1[w * 2 + 0] = s0;
                hs2[w * 2 + 1] = hs1[w * 2 + 1]; hs1[w * 2 + 1] = s1;
            }
            uintx2 ap;
            ap.x = pack_rne(a2[0], a2[1]);
            ap.y = pack_rne(a2[2], a2[3]);

            uintx2 al, ar;
            #pragma unroll
            for (int w = 0; w < 2; ++w) {
                al[w] = __shfl_up(ap[w], 2);
                ar[w] = __shfl_down(ap[w], 2);
            }
            uintx2 nh = pmax2(pmax2(al, ap), ar);
            uintx2 m3 = pmax2(pmax2(nh2, nh1), nh);
            nh2 = nh1; nh1 = nh;

            const int r2 = r - 1, r3 = r - 2;
            if (stcol && i >= 3 && i <= RB + 2)
                *(uintx2*)(cav + (size_t)((r2 - lo) * Wn + col) * 8) = ap;
            if (stcol && i >= 4) {
                uintx2 st;
                st.x = pack_rne(bf_lo(m5.x) + bf_lo(m3.x), bf_hi(m5.x) + bf_hi(m3.x));
                st.y = pack_rne(bf_lo(m5.y) + bf_lo(m3.y), bf_hi(m5.y) + bf_hi(m3.y));
                *(uintx2*)(cmx + (size_t)((r3 - lo) * Wn + col) * 8) = st;
            }
            cur = nxt; nxt = nx2;
        }
    }

    // ---- A-frags (w2 in k-slot layout) + bn2 constants: loads issue here,
    //      latency hides under the barrier wait ----
    const int m16 = lane & 15;
    const int q = lane >> 4;
    const int t = wv & 3;
    const int e = wv >> 2;
    short8 afr[4];
    #pragma unroll
    for (int cp = 0; cp < 4; ++cp) {
        const int c = 2 * cp + (q >> 1);
        const int chb = ((q & 1) ? 64 : 0) + 8 * c;   // k-slot -> cat channel base
        const float* wp = w2 + (size_t)(t * 16 + m16) * 128 + chb;
        floatx4 f0 = *(const floatx4*)wp;
        floatx4 f1 = *(const floatx4*)(wp + 4);
        uintx4 u;
        u.x = pack_rne(f0[0], f0[1]);
        u.y = pack_rne(f0[2], f0[3]);
        u.z = pack_rne(f1[0], f1[1]);
        u.w = pack_rne(f1[2], f1[3]);
        afr[cp] = *(short8*)&u;
    }
    const int oc0 = t * 16 + q * 4;     // this lane's 4 output channels
    floatx4 g4 = *(const floatx4*)(bg + oc0);
    floatx4 bb4 = *(const floatx4*)(bb + oc0);
    floatx4 mm4 = *(const floatx4*)(bm + oc0);
    floatx4 vv4 = *(const floatx4*)(bv + oc0);
    float sc[4], sh[4];
    #pragma unroll
    for (int r = 0; r < 4; ++r) {
        sc[r] = g4[r] * rsqrtf(vv4[r] + EPS);
        sh[r] = bb4[r] - mm4[r] * sc[r];
    }
    __syncthreads();

    // ---- Phase 2: MFMA. Wave = (t = wv&3, px-quarter e = wv>>2), 7 tiles ----
    floatx4 acc[7];
    #pragma unroll
    for (int i = 0; i < 7; ++i) acc[i] = (floatx4){0.f, 0.f, 0.f, 0.f};

    #pragma unroll
    for (int cp = 0; cp < 4; ++cp) {
        #pragma unroll
        for (int i = 0; i < 7; ++i) {
            const int px = (e * 7 + i) * 16 + m16;
            // slab = 4*cp + q: quads land at bank offsets {0,8,16,24}
            short8 bfr = *(const short8*)(catl + (size_t)(4 * cp + q) * SLAB + (size_t)px * 8);
            acc[i] = __builtin_amdgcn_mfma_f32_16x16x32_bf16(afr[cp], bfr, acc[i], 0, 0, 0);
        }
    }

    // ---- epilogue: bn2 + relu + fp32 store ----
    float* ob = out + (size_t)(b * 64 + oc0) * HWn + lo * Wn;
    #pragma unroll
    for (int i = 0; i < 7; ++i) {
        const int px = (e * 7 + i) * 16 + m16;
        #pragma unroll
        for (int r = 0; r < 4; ++r) {
            float v = fmaf(acc[i][r], sc[r], sh[r]);
            ob[(size_t)r * HWn + px] = v > 0.f ? v : 0.f;
        }
    }
}

extern "C" void kernel_launch(void* const* d_in, const int* in_sizes, int n_in,
                              void* d_out, int out_size, void* d_ws, size_t ws_size,
                              hipStream_t stream)
{
    const float* x   = (const float*)d_in[0];
    const float* w1  = (const float*)d_in[1];
    const float* w2  = (const float*)d_in[2];
    const float* b1g = (const float*)d_in[3];
    const float* b1b = (const float*)d_in[4];
    const float* b1m = (const float*)d_in[5];
    const float* b1v = (const float*)d_in[6];
    const float* b2g = (const float*)d_in[7];
    const float* b2b = (const float*)d_in[8];
    const float* b2m = (const float*)d_in[9];
    const float* b2v = (const float*)d_in[10];

    float* out = (float*)d_out;
    unsigned short* node0 = (unsigned short*)d_ws;            // 25.7 MB

    k1_conv1<<<dim3(784), dim3(256), 0, stream>>>(x, w1, b1g, b1b, b1m, b1v, node0);
    k23_fused<<<dim3(Bn * NBAND), dim3(1024), 0, stream>>>(node0, w2, b2g, b2b, b2m, b2v, out);
}